// Round 1
// baseline (307.311 us; speedup 1.0000x reference)
//
#include <hip/hip_runtime.h>

// Mutihead_Attention: x,y [2,2048,512] f32; Q=x@q_w^T+q_b etc.; the torch
// reshape(H,B,S,hd) is a FLAT reinterpretation: head-batch hb = h*2+b' owns the
// contiguous [2048,64] chunk at offset hb*131072 of the [4096,512] projection.
// scores = QK^T/sqrt(512); mask score<=rowmean -> 0 weight; softmax; PV; @o_w^T+o_b.
// rowmean_i = q_i . ksum / 2048 (ksum = column-sum of K chunk) => single pass.
// Accuracy: split-bf16 (hi/lo) MFMA for all GEMMs + QK^T (f32-like); plain bf16 PV.

typedef unsigned short ushort;
typedef unsigned int uint;

typedef __bf16  bf16x8  __attribute__((ext_vector_type(8)));
typedef float   floatx4 __attribute__((ext_vector_type(4)));
typedef float   float4v __attribute__((ext_vector_type(4)));
typedef uint    uint4v  __attribute__((ext_vector_type(4)));
typedef ushort  ushort4v __attribute__((ext_vector_type(4)));

#define MFMA16(a,b,c) __builtin_amdgcn_mfma_f32_16x16x32_bf16((a),(b),(c),0,0,0)

__device__ __forceinline__ float b2f(ushort u){
  union { uint i; float f; } v; v.i = ((uint)u) << 16; return v.f;
}
__device__ __forceinline__ ushort f2b(float f){   // RNE f32->bf16
  union { float f; uint i; } v; v.f = f;
  uint r = v.i + 0x7FFFu + ((v.i >> 16) & 1u);
  return (ushort)(r >> 16);
}
__device__ __forceinline__ void split2(float f, ushort& h, ushort& l){
  h = f2b(f);
  l = f2b(f - b2f(h));
}

// ---------------------------------------------------------------------------
// C[M,512] = X[M,512] @ W[512,512]^T + bias, split-bf16 MFMA (hi*hi+hi*lo+lo*hi).
// OUT_MODE 0: write f32 (C) to outf. 1: write hi/lo bf16. 2: write plain bf16.
// Block: 256 thr (4 waves, 2x2), tile BM=128 BN=64 BK=32.
// ---------------------------------------------------------------------------
template<int OUT_MODE>
__global__ __launch_bounds__(256) void proj_gemm(
    const float* __restrict__ X, const float* __restrict__ W,
    const float* __restrict__ bias,
    float* __restrict__ outf, ushort* __restrict__ outhi, ushort* __restrict__ outlo)
{
  const int m0 = blockIdx.x * 128;
  const int n0 = blockIdx.y * 64;

  __shared__ __align__(16) ushort Ahi[128][40];   // pad 32->40 hw (80B rows)
  __shared__ __align__(16) ushort Alo[128][40];
  __shared__ __align__(16) ushort Bhi[64][40];
  __shared__ __align__(16) ushort Blo[64][40];

  const int t    = threadIdx.x;
  const int lane = t & 63;
  const int wid  = t >> 6;
  const int wm   = wid >> 1, wn = wid & 1;
  const int lr   = lane & 15, lg = lane >> 4;

  floatx4 zf; zf[0]=0.f; zf[1]=0.f; zf[2]=0.f; zf[3]=0.f;
  floatx4 acc[4][2];
  #pragma unroll
  for (int i=0;i<4;i++)
    #pragma unroll
    for (int j=0;j<2;j++) acc[i][j] = zf;

  const int arow = t >> 3;         // 0..31
  const int acol = (t & 7) * 4;    // 0..28

  for (int k0 = 0; k0 < 512; k0 += 32) {
    __syncthreads();               // previous iteration's frag reads done
    // stage A tile 128x32 (f32 -> hi/lo bf16)
    #pragma unroll
    for (int p = 0; p < 4; p++) {
      int r = p*32 + arow;
      float4v d = *(const float4v*)&X[(size_t)(m0 + r)*512 + k0 + acol];
      ushort4v h, l;
      #pragma unroll
      for (int i=0;i<4;i++){ ushort hh, ll; split2(d[i], hh, ll); h[i]=hh; l[i]=ll; }
      *(ushort4v*)&Ahi[r][acol] = h;
      *(ushort4v*)&Alo[r][acol] = l;
    }
    // stage B tile 64x32
    #pragma unroll
    for (int p = 0; p < 2; p++) {
      int r = p*32 + arow;
      float4v d = *(const float4v*)&W[(size_t)(n0 + r)*512 + k0 + acol];
      ushort4v h, l;
      #pragma unroll
      for (int i=0;i<4;i++){ ushort hh, ll; split2(d[i], hh, ll); h[i]=hh; l[i]=ll; }
      *(ushort4v*)&Bhi[r][acol] = h;
      *(ushort4v*)&Blo[r][acol] = l;
    }
    __syncthreads();

    bf16x8 ah[4], al[4], bh[2], bl[2];
    #pragma unroll
    for (int mi=0;mi<4;mi++){
      ah[mi] = *(const bf16x8*)&Ahi[wm*64 + mi*16 + lr][lg*8];
      al[mi] = *(const bf16x8*)&Alo[wm*64 + mi*16 + lr][lg*8];
    }
    #pragma unroll
    for (int ni=0;ni<2;ni++){
      bh[ni] = *(const bf16x8*)&Bhi[wn*32 + ni*16 + lr][lg*8];
      bl[ni] = *(const bf16x8*)&Blo[wn*32 + ni*16 + lr][lg*8];
    }
    #pragma unroll
    for (int mi=0;mi<4;mi++)
      #pragma unroll
      for (int ni=0;ni<2;ni++){
        acc[mi][ni] = MFMA16(ah[mi], bh[ni], acc[mi][ni]);
        acc[mi][ni] = MFMA16(ah[mi], bl[ni], acc[mi][ni]);
        acc[mi][ni] = MFMA16(al[mi], bh[ni], acc[mi][ni]);
      }
  }

  // epilogue: D frag -> m = lg*4+r (row), n = lr (col)
  #pragma unroll
  for (int ni=0;ni<2;ni++){
    const int n = n0 + wn*32 + ni*16 + lr;
    const float bn = bias[n];
    #pragma unroll
    for (int mi=0;mi<4;mi++){
      #pragma unroll
      for (int r=0;r<4;r++){
        const int m = m0 + wm*64 + mi*16 + lg*4 + r;
        const float c = acc[mi][ni][r] + bn;
        const size_t off = (size_t)m*512 + n;
        if (OUT_MODE == 0)      { outf[off] = c; }
        else if (OUT_MODE == 1) { ushort h,l; split2(c,h,l); outhi[off]=h; outlo[off]=l; }
        else                    { outhi[off] = f2b(c); }
      }
    }
  }
}

// ---------------------------------------------------------------------------
// ksum[hb][d] = sum_s K_chunk[s][d]  (K stored as hi/lo bf16)
// ---------------------------------------------------------------------------
__global__ __launch_bounds__(256) void ksum_kernel(
    const ushort* __restrict__ khi, const ushort* __restrict__ klo,
    float* __restrict__ ksum)
{
  const int hb = blockIdx.x;
  const int t = threadIdx.x;
  const int d = t & 63, part = t >> 6;
  const size_t cb = (size_t)hb * 131072;
  float acc = 0.f;
  for (int s = part; s < 2048; s += 4) {
    size_t idx = cb + (size_t)s*64 + d;
    acc += b2f(khi[idx]) + b2f(klo[idx]);
  }
  __shared__ float red[256];
  red[t] = acc;
  __syncthreads();
  if (part == 0) ksum[hb*64 + d] = red[d] + red[64+d] + red[128+d] + red[192+d];
}

// ---------------------------------------------------------------------------
// Fused attention for one head-batch chunk: 64 q-rows per block, 4 waves,
// each wave owns 16 q-rows. Single pass over kv (mean threshold via ksum).
// ---------------------------------------------------------------------------
__global__ __launch_bounds__(256) void attn_kernel(
    const ushort* __restrict__ qhi, const ushort* __restrict__ qlo,
    const ushort* __restrict__ khi, const ushort* __restrict__ klo,
    const ushort* __restrict__ vv,  const float* __restrict__ ksum,
    float* __restrict__ attnout)
{
  const int hb = blockIdx.y;
  const int q0 = blockIdx.x * 64;
  const size_t cb = (size_t)hb * 131072;
  const float NF = 0.04419417382415922f;   // 1/sqrt(512)

  __shared__ __align__(16) ushort Qhi[64][72], Qlo[64][72];   // pad 64->72 hw
  __shared__ __align__(16) ushort Khi[64][72], Klo[64][72];
  __shared__ __align__(16) ushort Vt [64][72];                // V transposed [d][kv]
  __shared__ __align__(16) ushort Pl [64][72];                // P weights bf16 [q][kv]
  __shared__ float means[64];
  __shared__ float ksum_s[64];

  const int t = threadIdx.x, lane = t & 63, w = t >> 6;
  const int lr = lane & 15, lg = lane >> 4;
  const int srow = t >> 3;          // 0..31
  const int scol = (t & 7) * 8;     // 0..56

  // stage Q (once)
  #pragma unroll
  for (int p=0;p<2;p++){
    int r = p*32 + srow;
    size_t g = cb + (size_t)(q0 + r)*64 + scol;
    *(uint4v*)&Qhi[r][scol] = *(const uint4v*)&qhi[g];
    *(uint4v*)&Qlo[r][scol] = *(const uint4v*)&qlo[g];
  }
  if (t < 64) ksum_s[t] = ksum[hb*64 + t];
  __syncthreads();

  // raw row means (wave 0) + register-hoisted Q frags (all waves)
  if (t < 64){
    float m = 0.f;
    #pragma unroll 8
    for (int d=0; d<64; d++) m += (b2f(Qhi[t][d]) + b2f(Qlo[t][d])) * ksum_s[d];
    means[t] = m * (1.f/2048.f);
  }
  bf16x8 qfh[2], qfl[2];
  #pragma unroll
  for (int s=0;s<2;s++){
    qfh[s] = *(const bf16x8*)&Qhi[w*16 + lr][s*32 + lg*8];
    qfl[s] = *(const bf16x8*)&Qlo[w*16 + lr][s*32 + lg*8];
  }
  __syncthreads();

  float rm[4];
  #pragma unroll
  for (int r=0;r<4;r++) rm[r] = means[w*16 + lg*4 + r];

  floatx4 zf; zf[0]=0.f; zf[1]=0.f; zf[2]=0.f; zf[3]=0.f;
  floatx4 acc_o[4]; float z[4];
  #pragma unroll
  for (int i=0;i<4;i++){ acc_o[i] = zf; z[i] = 0.f; }

  for (int kt = 0; kt < 32; kt++){
    const int kvb = kt*64;
    // stage K hi/lo + V^T
    #pragma unroll
    for (int p=0;p<2;p++){
      int r = p*32 + srow;
      size_t g = cb + (size_t)(kvb + r)*64 + scol;
      *(uint4v*)&Khi[r][scol] = *(const uint4v*)&khi[g];
      *(uint4v*)&Klo[r][scol] = *(const uint4v*)&klo[g];
      uint4v dv = *(const uint4v*)&vv[g];
      #pragma unroll
      for (int j=0;j<8;j++)
        Vt[scol + j][r] = (ushort)(dv[j>>1] >> ((j&1)*16));
    }
    __syncthreads();

    // S tiles: S^ = Q.K^T raw dot; mask vs raw mean; exp; write P (wave-private rows)
    #pragma unroll
    for (int tk=0; tk<4; tk++){
      floatx4 s = zf;
      #pragma unroll
      for (int ks=0; ks<2; ks++){
        bf16x8 kh = *(const bf16x8*)&Khi[tk*16 + lr][ks*32 + lg*8];
        bf16x8 kl = *(const bf16x8*)&Klo[tk*16 + lr][ks*32 + lg*8];
        s = MFMA16(qfh[ks], kh, s);
        s = MFMA16(qfh[ks], kl, s);
        s = MFMA16(qfl[ks], kh, s);
      }
      #pragma unroll
      for (int r=0;r<4;r++){
        float raw = s[r];
        float p = (raw > rm[r]) ? __expf((raw - rm[r]) * NF) : 0.f;
        z[r] += p;
        Pl[w*16 + lg*4 + r][tk*16 + lr] = f2b(p);
      }
    }
    // PV: O += P.V   (P rows are wave-private; K/Vt protected by loop barriers)
    #pragma unroll
    for (int ks=0; ks<2; ks++){
      bf16x8 pf = *(const bf16x8*)&Pl[w*16 + lr][ks*32 + lg*8];
      #pragma unroll
      for (int dt=0; dt<4; dt++){
        bf16x8 vf = *(const bf16x8*)&Vt[dt*16 + lr][ks*32 + lg*8];
        acc_o[dt] = MFMA16(pf, vf, acc_o[dt]);
      }
    }
    __syncthreads();
  }

  // Z reduce across the 16 lanes sharing each q-row group
  #pragma unroll
  for (int r=0;r<4;r++){
    z[r] += __shfl_xor(z[r], 1);
    z[r] += __shfl_xor(z[r], 2);
    z[r] += __shfl_xor(z[r], 4);
    z[r] += __shfl_xor(z[r], 8);
    z[r] = 1.f / z[r];
  }
  #pragma unroll
  for (int dt=0; dt<4; dt++)
    #pragma unroll
    for (int r=0;r<4;r++){
      int q = q0 + w*16 + lg*4 + r;
      attnout[cb + (size_t)q*64 + dt*16 + lr] = acc_o[dt][r] * z[r];
    }
}

// ---------------------------------------------------------------------------
extern "C" void kernel_launch(void* const* d_in, const int* in_sizes, int n_in,
                              void* d_out, int out_size, void* d_ws, size_t ws_size,
                              hipStream_t stream)
{
  const float* x   = (const float*)d_in[0];
  const float* y   = (const float*)d_in[1];
  const float* q_w = (const float*)d_in[2];
  const float* q_b = (const float*)d_in[3];
  const float* k_w = (const float*)d_in[4];
  const float* k_b = (const float*)d_in[5];
  const float* v_w = (const float*)d_in[6];
  const float* v_b = (const float*)d_in[7];
  const float* o_w = (const float*)d_in[8];
  const float* o_b = (const float*)d_in[9];

  const size_t NE = 4096ull * 512;           // 2,097,152 elements per [4096,512]
  ushort* pq_hi = (ushort*)d_ws;             // ws layout: 5*4MB bf16 + 8MB f32 + 4KB
  ushort* pq_lo = pq_hi + NE;
  ushort* pk_hi = pq_lo + NE;
  ushort* pk_lo = pk_hi + NE;
  ushort* pv    = pk_lo + NE;
  float*  attno = (float*)(pv + NE);
  float*  ksumb = attno + NE;

  dim3 gg(32, 8), bb(256);
  proj_gemm<1><<<gg, bb, 0, stream>>>(x, q_w, q_b, nullptr, pq_hi, pq_lo);
  proj_gemm<1><<<gg, bb, 0, stream>>>(y, k_w, k_b, nullptr, pk_hi, pk_lo);
  proj_gemm<2><<<gg, bb, 0, stream>>>(y, v_w, v_b, nullptr, pv, nullptr);
  ksum_kernel<<<16, 256, 0, stream>>>(pk_hi, pk_lo, ksumb);
  attn_kernel<<<dim3(32,16), 256, 0, stream>>>(pq_hi, pq_lo, pk_hi, pk_lo, pv, ksumb, attno);
  proj_gemm<0><<<gg, bb, 0, stream>>>(attno, o_w, o_b, (float*)d_out, nullptr, nullptr);
}

// Round 2
// 186.819 us; speedup vs baseline: 1.6450x; 1.6450x over previous
//
#include <hip/hip_runtime.h>

// Mutihead_Attention: x,y [2,2048,512] f32; Q=x@q_w^T+q_b etc.; the torch
// reshape(H,B,S,hd) is a FLAT reinterpretation: head-batch hb = h*2+b' owns the
// contiguous [2048,64] chunk at offset hb*131072 of the [4096,512] projection.
// scores = QK^T/sqrt(512); mask score<=rowmean -> 0 weight; softmax; PV; @o_w^T+o_b.
// rowmean_i = q_i . ksum / 2048 (ksum = column-sum of K chunk) => single pass.
// ksum is FUSED into the K projection epilogue (R1: standalone ksum kernel was
// 125us latency-bound at 16 blocks). Accuracy: split-bf16 (hi/lo) MFMA for all
// GEMMs + QK^T (f32-like); plain bf16 PV.

typedef unsigned short ushort;
typedef unsigned int uint;

typedef __bf16  bf16x8  __attribute__((ext_vector_type(8)));
typedef float   floatx4 __attribute__((ext_vector_type(4)));
typedef float   float4v __attribute__((ext_vector_type(4)));
typedef uint    uint4v  __attribute__((ext_vector_type(4)));
typedef ushort  ushort4v __attribute__((ext_vector_type(4)));

#define MFMA16(a,b,c) __builtin_amdgcn_mfma_f32_16x16x32_bf16((a),(b),(c),0,0,0)

__device__ __forceinline__ float b2f(ushort u){
  union { uint i; float f; } v; v.i = ((uint)u) << 16; return v.f;
}
__device__ __forceinline__ ushort f2b(float f){   // RNE f32->bf16
  union { float f; uint i; } v; v.f = f;
  uint r = v.i + 0x7FFFu + ((v.i >> 16) & 1u);
  return (ushort)(r >> 16);
}
__device__ __forceinline__ void split2(float f, ushort& h, ushort& l){
  h = f2b(f);
  l = f2b(f - b2f(h));
}

// ---------------------------------------------------------------------------
// C[M,512] = X[M,512] @ W[512,512]^T + bias, split-bf16 MFMA (hi*hi+hi*lo+lo*hi).
// OUT_MODE 0: write f32 (C) to outf. 1: write hi/lo bf16. 2: write plain bf16.
// KSUM: fused per-hb column sums (reshape d = n&63) atomicAdd'ed to ksum_out.
// Block: 256 thr (4 waves, 2x2), tile BM=128 BN=64 BK=32.
// ---------------------------------------------------------------------------
template<int OUT_MODE, bool KSUM>
__global__ __launch_bounds__(256) void proj_gemm(
    const float* __restrict__ X, const float* __restrict__ W,
    const float* __restrict__ bias,
    float* __restrict__ outf, ushort* __restrict__ outhi, ushort* __restrict__ outlo,
    float* __restrict__ ksum_out)
{
  const int m0 = blockIdx.x * 128;
  const int n0 = blockIdx.y * 64;

  __shared__ __align__(16) ushort Ahi[128][40];   // pad 32->40 hw (80B rows)
  __shared__ __align__(16) ushort Alo[128][40];
  __shared__ __align__(16) ushort Bhi[64][40];
  __shared__ __align__(16) ushort Blo[64][40];
  __shared__ float cs[64];                         // KSUM column reduce

  const int t    = threadIdx.x;
  const int lane = t & 63;
  const int wid  = t >> 6;
  const int wm   = wid >> 1, wn = wid & 1;
  const int lr   = lane & 15, lg = lane >> 4;

  floatx4 zf; zf[0]=0.f; zf[1]=0.f; zf[2]=0.f; zf[3]=0.f;
  floatx4 acc[4][2];
  #pragma unroll
  for (int i=0;i<4;i++)
    #pragma unroll
    for (int j=0;j<2;j++) acc[i][j] = zf;

  const int arow = t >> 3;         // 0..31
  const int acol = (t & 7) * 4;    // 0..28

  for (int k0 = 0; k0 < 512; k0 += 32) {
    __syncthreads();               // previous iteration's frag reads done
    // stage A tile 128x32 (f32 -> hi/lo bf16)
    #pragma unroll
    for (int p = 0; p < 4; p++) {
      int r = p*32 + arow;
      float4v d = *(const float4v*)&X[(size_t)(m0 + r)*512 + k0 + acol];
      ushort4v h, l;
      #pragma unroll
      for (int i=0;i<4;i++){ ushort hh, ll; split2(d[i], hh, ll); h[i]=hh; l[i]=ll; }
      *(ushort4v*)&Ahi[r][acol] = h;
      *(ushort4v*)&Alo[r][acol] = l;
    }
    // stage B tile 64x32
    #pragma unroll
    for (int p = 0; p < 2; p++) {
      int r = p*32 + arow;
      float4v d = *(const float4v*)&W[(size_t)(n0 + r)*512 + k0 + acol];
      ushort4v h, l;
      #pragma unroll
      for (int i=0;i<4;i++){ ushort hh, ll; split2(d[i], hh, ll); h[i]=hh; l[i]=ll; }
      *(ushort4v*)&Bhi[r][acol] = h;
      *(ushort4v*)&Blo[r][acol] = l;
    }
    __syncthreads();

    bf16x8 ah[4], al[4], bh[2], bl[2];
    #pragma unroll
    for (int mi=0;mi<4;mi++){
      ah[mi] = *(const bf16x8*)&Ahi[wm*64 + mi*16 + lr][lg*8];
      al[mi] = *(const bf16x8*)&Alo[wm*64 + mi*16 + lr][lg*8];
    }
    #pragma unroll
    for (int ni=0;ni<2;ni++){
      bh[ni] = *(const bf16x8*)&Bhi[wn*32 + ni*16 + lr][lg*8];
      bl[ni] = *(const bf16x8*)&Blo[wn*32 + ni*16 + lr][lg*8];
    }
    #pragma unroll
    for (int mi=0;mi<4;mi++)
      #pragma unroll
      for (int ni=0;ni<2;ni++){
        acc[mi][ni] = MFMA16(ah[mi], bh[ni], acc[mi][ni]);
        acc[mi][ni] = MFMA16(ah[mi], bl[ni], acc[mi][ni]);
        acc[mi][ni] = MFMA16(al[mi], bh[ni], acc[mi][ni]);
      }
  }

  // epilogue: D frag -> m = lg*4+r (row), n = lr (col)
  #pragma unroll
  for (int ni=0;ni<2;ni++){
    const int n = n0 + wn*32 + ni*16 + lr;
    const float bn = bias[n];
    #pragma unroll
    for (int mi=0;mi<4;mi++){
      #pragma unroll
      for (int r=0;r<4;r++){
        const int m = m0 + wm*64 + mi*16 + lg*4 + r;
        const float c = acc[mi][ni][r] + bn;
        const size_t off = (size_t)m*512 + n;
        if (OUT_MODE == 0)      { outf[off] = c; }
        else if (OUT_MODE == 1) { ushort h,l; split2(c,h,l); outhi[off]=h; outlo[off]=l; }
        else                    { outhi[off] = f2b(c); }
      }
    }
  }

  // fused ksum: this block's 128 rows live in one hb chunk (128 | 256);
  // column n contributes to d = n&63 = wn*32+ni*16+lr. 8 threads/column.
  if (KSUM) {
    if (t < 64) cs[t] = 0.f;
    __syncthreads();
    #pragma unroll
    for (int ni=0;ni<2;ni++){
      float s = 0.f;
      #pragma unroll
      for (int mi=0;mi<4;mi++)
        #pragma unroll
        for (int r=0;r<4;r++) s += acc[mi][ni][r];
      atomicAdd(&cs[wn*32 + ni*16 + lr], s);
    }
    __syncthreads();
    if (t < 64){
      const int hb = m0 >> 8;
      atomicAdd(&ksum_out[hb*64 + t], cs[t] + 128.f * bias[n0 + t]);
    }
  }
}

// ---------------------------------------------------------------------------
// Fused attention for one head-batch chunk: 64 q-rows per block, 4 waves,
// each wave owns 16 q-rows. Single pass over kv (mean threshold via ksum).
// ---------------------------------------------------------------------------
__global__ __launch_bounds__(256) void attn_kernel(
    const ushort* __restrict__ qhi, const ushort* __restrict__ qlo,
    const ushort* __restrict__ khi, const ushort* __restrict__ klo,
    const ushort* __restrict__ vv,  const float* __restrict__ ksum,
    float* __restrict__ attnout)
{
  const int hb = blockIdx.y;
  const int q0 = blockIdx.x * 64;
  const size_t cb = (size_t)hb * 131072;
  const float NF = 0.04419417382415922f;   // 1/sqrt(512)

  __shared__ __align__(16) ushort Qhi[64][72], Qlo[64][72];   // pad 64->72 hw
  __shared__ __align__(16) ushort Khi[64][72], Klo[64][72];
  __shared__ __align__(16) ushort Vt [64][72];                // V transposed [d][kv]
  __shared__ __align__(16) ushort Pl [64][72];                // P weights bf16 [q][kv]
  __shared__ float means[64];
  __shared__ float ksum_s[64];

  const int t = threadIdx.x, lane = t & 63, w = t >> 6;
  const int lr = lane & 15, lg = lane >> 4;
  const int srow = t >> 3;          // 0..31
  const int scol = (t & 7) * 8;     // 0..56

  // stage Q (once)
  #pragma unroll
  for (int p=0;p<2;p++){
    int r = p*32 + srow;
    size_t g = cb + (size_t)(q0 + r)*64 + scol;
    *(uint4v*)&Qhi[r][scol] = *(const uint4v*)&qhi[g];
    *(uint4v*)&Qlo[r][scol] = *(const uint4v*)&qlo[g];
  }
  if (t < 64) ksum_s[t] = ksum[hb*64 + t];
  __syncthreads();

  // raw row means (wave 0) + register-hoisted Q frags (all waves)
  if (t < 64){
    float m = 0.f;
    #pragma unroll 8
    for (int d=0; d<64; d++) m += (b2f(Qhi[t][d]) + b2f(Qlo[t][d])) * ksum_s[d];
    means[t] = m * (1.f/2048.f);
  }
  bf16x8 qfh[2], qfl[2];
  #pragma unroll
  for (int s=0;s<2;s++){
    qfh[s] = *(const bf16x8*)&Qhi[w*16 + lr][s*32 + lg*8];
    qfl[s] = *(const bf16x8*)&Qlo[w*16 + lr][s*32 + lg*8];
  }
  __syncthreads();

  float rm[4];
  #pragma unroll
  for (int r=0;r<4;r++) rm[r] = means[w*16 + lg*4 + r];

  floatx4 zf; zf[0]=0.f; zf[1]=0.f; zf[2]=0.f; zf[3]=0.f;
  floatx4 acc_o[4]; float z[4];
  #pragma unroll
  for (int i=0;i<4;i++){ acc_o[i] = zf; z[i] = 0.f; }

  for (int kt = 0; kt < 32; kt++){
    const int kvb = kt*64;
    // stage K hi/lo + V^T
    #pragma unroll
    for (int p=0;p<2;p++){
      int r = p*32 + srow;
      size_t g = cb + (size_t)(kvb + r)*64 + scol;
      *(uint4v*)&Khi[r][scol] = *(const uint4v*)&khi[g];
      *(uint4v*)&Klo[r][scol] = *(const uint4v*)&klo[g];
      uint4v dv = *(const uint4v*)&vv[g];
      #pragma unroll
      for (int j=0;j<8;j++)
        Vt[scol + j][r] = (ushort)(dv[j>>1] >> ((j&1)*16));
    }
    __syncthreads();

    // S tiles: S^ = Q.K^T raw dot; mask vs raw mean; exp; write P (wave-private rows)
    #pragma unroll
    for (int tk=0; tk<4; tk++){
      floatx4 s = zf;
      #pragma unroll
      for (int ks=0; ks<2; ks++){
        bf16x8 kh = *(const bf16x8*)&Khi[tk*16 + lr][ks*32 + lg*8];
        bf16x8 kl = *(const bf16x8*)&Klo[tk*16 + lr][ks*32 + lg*8];
        s = MFMA16(qfh[ks], kh, s);
        s = MFMA16(qfh[ks], kl, s);
        s = MFMA16(qfl[ks], kh, s);
      }
      #pragma unroll
      for (int r=0;r<4;r++){
        float raw = s[r];
        float p = (raw > rm[r]) ? __expf((raw - rm[r]) * NF) : 0.f;
        z[r] += p;
        Pl[w*16 + lg*4 + r][tk*16 + lr] = f2b(p);
      }
    }
    // PV: O += P.V   (P rows are wave-private; K/Vt protected by loop barriers)
    #pragma unroll
    for (int ks=0; ks<2; ks++){
      bf16x8 pf = *(const bf16x8*)&Pl[w*16 + lr][ks*32 + lg*8];
      #pragma unroll
      for (int dt=0; dt<4; dt++){
        bf16x8 vf = *(const bf16x8*)&Vt[dt*16 + lr][ks*32 + lg*8];
        acc_o[dt] = MFMA16(pf, vf, acc_o[dt]);
      }
    }
    __syncthreads();
  }

  // Z reduce across the 16 lanes sharing each q-row group
  #pragma unroll
  for (int r=0;r<4;r++){
    z[r] += __shfl_xor(z[r], 1);
    z[r] += __shfl_xor(z[r], 2);
    z[r] += __shfl_xor(z[r], 4);
    z[r] += __shfl_xor(z[r], 8);
    z[r] = 1.f / z[r];
  }
  #pragma unroll
  for (int dt=0; dt<4; dt++)
    #pragma unroll
    for (int r=0;r<4;r++){
      int q = q0 + w*16 + lg*4 + r;
      attnout[cb + (size_t)q*64 + dt*16 + lr] = acc_o[dt][r] * z[r];
    }
}

// ---------------------------------------------------------------------------
extern "C" void kernel_launch(void* const* d_in, const int* in_sizes, int n_in,
                              void* d_out, int out_size, void* d_ws, size_t ws_size,
                              hipStream_t stream)
{
  const float* x   = (const float*)d_in[0];
  const float* y   = (const float*)d_in[1];
  const float* q_w = (const float*)d_in[2];
  const float* q_b = (const float*)d_in[3];
  const float* k_w = (const float*)d_in[4];
  const float* k_b = (const float*)d_in[5];
  const float* v_w = (const float*)d_in[6];
  const float* v_b = (const float*)d_in[7];
  const float* o_w = (const float*)d_in[8];
  const float* o_b = (const float*)d_in[9];

  const size_t NE = 4096ull * 512;           // 2,097,152 elements per [4096,512]
  ushort* pq_hi = (ushort*)d_ws;             // ws layout: 5*4MB bf16 + 8MB f32 + 4KB
  ushort* pq_lo = pq_hi + NE;
  ushort* pk_hi = pq_lo + NE;
  ushort* pk_lo = pk_hi + NE;
  ushort* pv    = pk_lo + NE;
  float*  attno = (float*)(pv + NE);
  float*  ksumb = attno + NE;

  hipMemsetAsync(ksumb, 0, 16 * 64 * sizeof(float), stream);

  dim3 gg(32, 8), bb(256);
  proj_gemm<1,false><<<gg, bb, 0, stream>>>(x, q_w, q_b, nullptr, pq_hi, pq_lo, nullptr);
  proj_gemm<1,true ><<<gg, bb, 0, stream>>>(y, k_w, k_b, nullptr, pk_hi, pk_lo, ksumb);
  proj_gemm<2,false><<<gg, bb, 0, stream>>>(y, v_w, v_b, nullptr, pv, nullptr, nullptr);
  attn_kernel<<<dim3(32,16), 256, 0, stream>>>(pq_hi, pq_lo, pk_hi, pk_lo, pv, ksumb, attno);
  proj_gemm<0,false><<<gg, bb, 0, stream>>>(attno, o_w, o_b, (float*)d_out, nullptr, nullptr, nullptr);
}

// Round 3
// 159.982 us; speedup vs baseline: 1.9209x; 1.1678x over previous
//
#include <hip/hip_runtime.h>

// Mutihead_Attention: x,y [2,2048,512] f32; Q=x@q_w^T+q_b etc.; the torch
// reshape(H,B,S,hd) is a FLAT reinterpretation: head-batch hb = h*2+b' owns the
// contiguous [2048,64] chunk at offset hb*131072 of the [4096,512] projection.
// scores = QK^T/sqrt(512); mask score<=rowmean -> 0 weight; softmax; PV; @o_w^T+o_b.
// rowmean_i = q_i . ksum / 2048 (ksum fused into K-proj epilogue, R1).
// R2: attn rewritten — V pre-transposed (vtrans kernel; in-attn u16 transpose was a
// 16-way bank conflict = 37% of cycles), linear LDS + 16B-block XOR swizzle
// (bank-balanced), global_load_lds(16) staging with pre-swizzled global source,
// double-buffered K/V tiles (1 barrier/iter), Q frags direct from global.

typedef unsigned short ushort;
typedef unsigned int uint;

typedef __bf16  bf16x8  __attribute__((ext_vector_type(8)));
typedef float   floatx4 __attribute__((ext_vector_type(4)));
typedef float   float4v __attribute__((ext_vector_type(4)));
typedef uint    uint4v  __attribute__((ext_vector_type(4)));
typedef ushort  ushort4v __attribute__((ext_vector_type(4)));

#define MFMA16(a,b,c) __builtin_amdgcn_mfma_f32_16x16x32_bf16((a),(b),(c),0,0,0)

__device__ __forceinline__ float b2f(ushort u){
  union { uint i; float f; } v; v.i = ((uint)u) << 16; return v.f;
}
__device__ __forceinline__ ushort f2b(float f){   // RNE f32->bf16
  union { float f; uint i; } v; v.f = f;
  uint r = v.i + 0x7FFFu + ((v.i >> 16) & 1u);
  return (ushort)(r >> 16);
}
__device__ __forceinline__ void split2(float f, ushort& h, ushort& l){
  h = f2b(f);
  l = f2b(f - b2f(h));
}
// async global->LDS 16B: LDS dest is wave-uniform base + lane*16 (m104)
__device__ __forceinline__ void gload16(const ushort* g, ushort* l){
  __builtin_amdgcn_global_load_lds(
      (const __attribute__((address_space(1))) unsigned int*)g,
      (__attribute__((address_space(3))) unsigned int*)l, 16, 0, 0);
}

// ---------------------------------------------------------------------------
// C[M,512] = X[M,512] @ W[512,512]^T + bias, split-bf16 MFMA (hi*hi+hi*lo+lo*hi).
// OUT_MODE 0: write f32. 1: write hi/lo bf16. 2: write plain bf16.
// KSUM: fused per-hb column sums (reshape d = n&63) atomicAdd'ed to ksum_out.
// ---------------------------------------------------------------------------
template<int OUT_MODE, bool KSUM>
__global__ __launch_bounds__(256) void proj_gemm(
    const float* __restrict__ X, const float* __restrict__ W,
    const float* __restrict__ bias,
    float* __restrict__ outf, ushort* __restrict__ outhi, ushort* __restrict__ outlo,
    float* __restrict__ ksum_out)
{
  const int m0 = blockIdx.x * 128;
  const int n0 = blockIdx.y * 64;

  __shared__ __align__(16) ushort Ahi[128][40];
  __shared__ __align__(16) ushort Alo[128][40];
  __shared__ __align__(16) ushort Bhi[64][40];
  __shared__ __align__(16) ushort Blo[64][40];
  __shared__ float cs[64];

  const int t    = threadIdx.x;
  const int lane = t & 63;
  const int wid  = t >> 6;
  const int wm   = wid >> 1, wn = wid & 1;
  const int lr   = lane & 15, lg = lane >> 4;

  floatx4 zf; zf[0]=0.f; zf[1]=0.f; zf[2]=0.f; zf[3]=0.f;
  floatx4 acc[4][2];
  #pragma unroll
  for (int i=0;i<4;i++)
    #pragma unroll
    for (int j=0;j<2;j++) acc[i][j] = zf;

  const int arow = t >> 3;
  const int acol = (t & 7) * 4;

  for (int k0 = 0; k0 < 512; k0 += 32) {
    __syncthreads();
    #pragma unroll
    for (int p = 0; p < 4; p++) {
      int r = p*32 + arow;
      float4v d = *(const float4v*)&X[(size_t)(m0 + r)*512 + k0 + acol];
      ushort4v h, l;
      #pragma unroll
      for (int i=0;i<4;i++){ ushort hh, ll; split2(d[i], hh, ll); h[i]=hh; l[i]=ll; }
      *(ushort4v*)&Ahi[r][acol] = h;
      *(ushort4v*)&Alo[r][acol] = l;
    }
    #pragma unroll
    for (int p = 0; p < 2; p++) {
      int r = p*32 + arow;
      float4v d = *(const float4v*)&W[(size_t)(n0 + r)*512 + k0 + acol];
      ushort4v h, l;
      #pragma unroll
      for (int i=0;i<4;i++){ ushort hh, ll; split2(d[i], hh, ll); h[i]=hh; l[i]=ll; }
      *(ushort4v*)&Bhi[r][acol] = h;
      *(ushort4v*)&Blo[r][acol] = l;
    }
    __syncthreads();

    bf16x8 ah[4], al[4], bh[2], bl[2];
    #pragma unroll
    for (int mi=0;mi<4;mi++){
      ah[mi] = *(const bf16x8*)&Ahi[wm*64 + mi*16 + lr][lg*8];
      al[mi] = *(const bf16x8*)&Alo[wm*64 + mi*16 + lr][lg*8];
    }
    #pragma unroll
    for (int ni=0;ni<2;ni++){
      bh[ni] = *(const bf16x8*)&Bhi[wn*32 + ni*16 + lr][lg*8];
      bl[ni] = *(const bf16x8*)&Blo[wn*32 + ni*16 + lr][lg*8];
    }
    #pragma unroll
    for (int mi=0;mi<4;mi++)
      #pragma unroll
      for (int ni=0;ni<2;ni++){
        acc[mi][ni] = MFMA16(ah[mi], bh[ni], acc[mi][ni]);
        acc[mi][ni] = MFMA16(ah[mi], bl[ni], acc[mi][ni]);
        acc[mi][ni] = MFMA16(al[mi], bh[ni], acc[mi][ni]);
      }
  }

  #pragma unroll
  for (int ni=0;ni<2;ni++){
    const int n = n0 + wn*32 + ni*16 + lr;
    const float bn = bias[n];
    #pragma unroll
    for (int mi=0;mi<4;mi++){
      #pragma unroll
      for (int r=0;r<4;r++){
        const int m = m0 + wm*64 + mi*16 + lg*4 + r;
        const float c = acc[mi][ni][r] + bn;
        const size_t off = (size_t)m*512 + n;
        if (OUT_MODE == 0)      { outf[off] = c; }
        else if (OUT_MODE == 1) { ushort h,l; split2(c,h,l); outhi[off]=h; outlo[off]=l; }
        else                    { outhi[off] = f2b(c); }
      }
    }
  }

  if (KSUM) {
    if (t < 64) cs[t] = 0.f;
    __syncthreads();
    #pragma unroll
    for (int ni=0;ni<2;ni++){
      float s = 0.f;
      #pragma unroll
      for (int mi=0;mi<4;mi++)
        #pragma unroll
        for (int r=0;r<4;r++) s += acc[mi][ni][r];
      atomicAdd(&cs[wn*32 + ni*16 + lr], s);
    }
    __syncthreads();
    if (t < 64){
      const int hb = m0 >> 8;
      atomicAdd(&ksum_out[hb*64 + t], cs[t] + 128.f * bias[n0 + t]);
    }
  }
}

// ---------------------------------------------------------------------------
// vt[hb][d][s] = pv[hb][s][d]  (64x64 LDS-tiled transpose, coalesced both sides)
// ---------------------------------------------------------------------------
__global__ __launch_bounds__(256) void vtrans(
    const ushort* __restrict__ pv, ushort* __restrict__ vt)
{
  const int hb = blockIdx.y;
  const int s0 = blockIdx.x * 64;
  const size_t cb = (size_t)hb * 131072;
  __shared__ __align__(16) ushort T[64][68];
  const int t = threadIdx.x;
  {
    int s = t >> 2, c = (t & 3) * 16;
    *(uint4v*)&T[s][c]     = *(const uint4v*)&pv[cb + (size_t)(s0+s)*64 + c];
    *(uint4v*)&T[s][c + 8] = *(const uint4v*)&pv[cb + (size_t)(s0+s)*64 + c + 8];
  }
  __syncthreads();
  const int d = t >> 2, sc = (t & 3) * 16;
  ushort buf[16];
  #pragma unroll
  for (int i=0;i<16;i++) buf[i] = T[sc + i][d];
  *(uint4v*)&vt[cb + (size_t)d*2048 + s0 + sc]     = *(const uint4v*)&buf[0];
  *(uint4v*)&vt[cb + (size_t)d*2048 + s0 + sc + 8] = *(const uint4v*)&buf[8];
}

// ---------------------------------------------------------------------------
// Fused attention, one hb chunk, 64 q-rows/block, 4 waves (16 q-rows each).
// LDS arrays are linear [64][64] halves with 16B-block XOR swizzle:
//   lds_half(row, col) = row*64 + (((col>>3) ^ (row&7))<<3) + (col&7)
// staged by global_load_lds(16B) with the inverse swizzle on the GLOBAL address.
// K/V double-buffered: stage(kt+1) issued before compute(kt), 1 barrier/iter.
// ---------------------------------------------------------------------------
__device__ __forceinline__ void stage_tile(
    ushort* khb, ushort* klb, ushort* vtb,
    const ushort* gkhi, const ushort* gklo, const ushort* gvt,
    size_t cb, int kvb, int w, int l)
{
  const int rsub = l >> 3;            // row within 8-row chunk; row&7 == rsub
  const int c8   = (l & 7) ^ rsub;    // pre-swizzled source 16B-block index
  #pragma unroll
  for (int j = 0; j < 6; j++){
    const int chunk = w*6 + j;        // 24 x 1KB chunks: 8 KH, 8 KL, 8 VT
    const int a   = chunk >> 3;
    const int sub = chunk & 7;
    const int row = sub*8 + rsub;
    if (a == 0)
      gload16(gkhi + cb + (size_t)(kvb + row)*64 + c8*8, khb + sub*512);
    else if (a == 1)
      gload16(gklo + cb + (size_t)(kvb + row)*64 + c8*8, klb + sub*512);
    else
      gload16(gvt  + cb + (size_t)row*2048 + kvb + c8*8, vtb + sub*512);
  }
}

__global__ __launch_bounds__(256) void attn_kernel(
    const ushort* __restrict__ qhi, const ushort* __restrict__ qlo,
    const ushort* __restrict__ khi, const ushort* __restrict__ klo,
    const ushort* __restrict__ vt,  const float* __restrict__ ksum,
    float* __restrict__ attnout)
{
  const int hb = blockIdx.y;
  const int q0 = blockIdx.x * 64;
  const size_t cb = (size_t)hb * 131072;
  const float NF = 0.04419417382415922f;   // 1/sqrt(512)

  __shared__ __align__(16) ushort KH [2][4096];
  __shared__ __align__(16) ushort KL [2][4096];
  __shared__ __align__(16) ushort VTs[2][4096];
  __shared__ __align__(16) ushort PL [4096];
  __shared__ float means[64];

  const int t = threadIdx.x, l = t & 63, w = t >> 6;
  const int lr = l & 15, lg = l >> 4;

  // issue tile-0 staging first; Q/means work hides its latency
  stage_tile(KH[0], KL[0], VTs[0], khi, klo, vt, cb, 0, w, l);

  // Q frags direct from global (A-frag: q-row = lr, d = s*32+lg*8..+7)
  union U8 { bf16x8 v; ushort u[8]; };
  U8 qfh[2], qfl[2];
  float part = 0.f;
  #pragma unroll
  for (int s=0;s<2;s++){
    size_t g = cb + (size_t)(q0 + w*16 + lr)*64 + s*32 + lg*8;
    qfh[s].v = *(const bf16x8*)&qhi[g];
    qfl[s].v = *(const bf16x8*)&qlo[g];
    float4v k0 = *(const float4v*)&ksum[hb*64 + s*32 + lg*8];
    float4v k1 = *(const float4v*)&ksum[hb*64 + s*32 + lg*8 + 4];
    #pragma unroll
    for (int j=0;j<4;j++) part += (b2f(qfh[s].u[j])   + b2f(qfl[s].u[j]))   * k0[j];
    #pragma unroll
    for (int j=0;j<4;j++) part += (b2f(qfh[s].u[4+j]) + b2f(qfl[s].u[4+j])) * k1[j];
  }
  // reduce over the 4 lanes sharing q-row lr (l, l^16, l^32, l^48)
  part += __shfl_xor(part, 16);
  part += __shfl_xor(part, 32);
  if (l < 16) means[w*16 + l] = part * (1.f/2048.f);
  __syncthreads();                       // tile-0 staged + means visible

  float rm[4];
  #pragma unroll
  for (int r=0;r<4;r++) rm[r] = means[w*16 + lg*4 + r];

  floatx4 zf; zf[0]=0.f; zf[1]=0.f; zf[2]=0.f; zf[3]=0.f;
  floatx4 acc_o[4]; float z[4];
  #pragma unroll
  for (int i=0;i<4;i++){ acc_o[i] = zf; z[i] = 0.f; }

  int cur = 0;
  for (int kt = 0; kt < 32; kt++){
    if (kt + 1 < 32)
      stage_tile(KH[cur^1], KL[cur^1], VTs[cur^1], khi, klo, vt, cb, (kt+1)*64, w, l);

    const ushort* KHc = KH[cur];
    const ushort* KLc = KL[cur];
    const ushort* VTc = VTs[cur];

    // QK^T (split-bf16, 3 MFMA) -> mask vs raw mean -> exp -> P (swizzled LDS)
    #pragma unroll
    for (int tk=0; tk<4; tk++){
      floatx4 s = zf;
      #pragma unroll
      for (int ks=0; ks<2; ks++){
        const int off = (tk*16 + lr)*64 + (((ks*4 + lg) ^ (lr & 7)) << 3);
        bf16x8 kh = *(const bf16x8*)&KHc[off];
        bf16x8 kl2 = *(const bf16x8*)&KLc[off];
        s = MFMA16(qfh[ks].v, kh,  s);
        s = MFMA16(qfh[ks].v, kl2, s);
        s = MFMA16(qfl[ks].v, kh,  s);
      }
      #pragma unroll
      for (int r=0;r<4;r++){
        float raw = s[r];
        float p = (raw > rm[r]) ? __expf((raw - rm[r]) * NF) : 0.f;
        z[r] += p;
        const int row = w*16 + lg*4 + r;
        PL[row*64 + (((tk*2 + (lr>>3)) ^ (row & 7)) << 3) + (lr & 7)] = f2b(p);
      }
    }
    // PV: O += P.V (P rows wave-private; lgkmcnt ordering within wave suffices)
    #pragma unroll
    for (int ks=0; ks<2; ks++){
      const int poff = (w*16 + lr)*64 + (((ks*4 + lg) ^ (lr & 7)) << 3);
      bf16x8 pf = *(const bf16x8*)&PL[poff];
      #pragma unroll
      for (int dt=0; dt<4; dt++){
        const int voff = (dt*16 + lr)*64 + (((ks*4 + lg) ^ (lr & 7)) << 3);
        bf16x8 vf = *(const bf16x8*)&VTc[voff];
        acc_o[dt] = MFMA16(pf, vf, acc_o[dt]);
      }
    }
    __syncthreads();   // all reads of cur done + next tile staged (vmcnt drain)
    cur ^= 1;
  }

  #pragma unroll
  for (int r=0;r<4;r++){
    z[r] += __shfl_xor(z[r], 1);
    z[r] += __shfl_xor(z[r], 2);
    z[r] += __shfl_xor(z[r], 4);
    z[r] += __shfl_xor(z[r], 8);
    z[r] = 1.f / z[r];
  }
  #pragma unroll
  for (int dt=0; dt<4; dt++)
    #pragma unroll
    for (int r=0;r<4;r++){
      int q = q0 + w*16 + lg*4 + r;
      attnout[cb + (size_t)q*64 + dt*16 + lr] = acc_o[dt][r] * z[r];
    }
}

// ---------------------------------------------------------------------------
extern "C" void kernel_launch(void* const* d_in, const int* in_sizes, int n_in,
                              void* d_out, int out_size, void* d_ws, size_t ws_size,
                              hipStream_t stream)
{
  const float* x   = (const float*)d_in[0];
  const float* y   = (const float*)d_in[1];
  const float* q_w = (const float*)d_in[2];
  const float* q_b = (const float*)d_in[3];
  const float* k_w = (const float*)d_in[4];
  const float* k_b = (const float*)d_in[5];
  const float* v_w = (const float*)d_in[6];
  const float* v_b = (const float*)d_in[7];
  const float* o_w = (const float*)d_in[8];
  const float* o_b = (const float*)d_in[9];

  const size_t NE = 4096ull * 512;
  ushort* pq_hi = (ushort*)d_ws;     // 6 x 4MB bf16 + 8MB f32 + 4KB
  ushort* pq_lo = pq_hi + NE;
  ushort* pk_hi = pq_lo + NE;
  ushort* pk_lo = pk_hi + NE;
  ushort* pv    = pk_lo + NE;
  ushort* vtg   = pv    + NE;
  float*  attno = (float*)(vtg + NE);
  float*  ksumb = attno + NE;

  hipMemsetAsync(ksumb, 0, 16 * 64 * sizeof(float), stream);

  dim3 gg(32, 8), bb(256);
  proj_gemm<1,false><<<gg, bb, 0, stream>>>(x, q_w, q_b, nullptr, pq_hi, pq_lo, nullptr);
  proj_gemm<1,true ><<<gg, bb, 0, stream>>>(y, k_w, k_b, nullptr, pk_hi, pk_lo, ksumb);
  proj_gemm<2,false><<<gg, bb, 0, stream>>>(y, v_w, v_b, nullptr, pv, nullptr, nullptr);
  vtrans<<<dim3(32,16), 256, 0, stream>>>(pv, vtg);
  attn_kernel<<<dim3(32,16), 256, 0, stream>>>(pq_hi, pq_lo, pk_hi, pk_lo, vtg, ksumb, attno);
  proj_gemm<0,false><<<gg, bb, 0, stream>>>(attno, o_w, o_b, (float*)d_out, nullptr, nullptr, nullptr);
}

// Round 4
// 134.224 us; speedup vs baseline: 2.2895x; 1.1919x over previous
//
#include <hip/hip_runtime.h>

// Mutihead_Attention: x,y [2,2048,512] f32. Flat-reshape => head-batch hb owns
// contiguous [2048,64] chunk at hb*131072 of each [4096,512] projection.
// scores=QK^T/sqrt(512); mask score<=rowmean; softmax; PV; @o_w^T+o_b.
// rowmean_i = q_i.ksum/2048 (ksum fused in K-proj epilogue).
// R4: (a) inputs/weights pre-split to hi/lo bf16 once (proj GEMMs were VALU/latency
// bound re-converting f32 per block); proj GEMMs now gload_lds(16)+dbuf, BK=64.
// (b) attn: 32x32x16 MFMA, swapped QK^T (C[key][q], q=lane&31 -> rm lane-local),
// in-register P via v_cvt_pk_bf16_f32 + v_permlane32_swap_b32 (T12) -> no P LDS;
// 32 q-rows/wave halves K/V LDS reads per row. attn out = plain bf16.

typedef unsigned short ushort;
typedef unsigned int uint;

typedef __bf16  bf16x8   __attribute__((ext_vector_type(8)));
typedef float   floatx4  __attribute__((ext_vector_type(4)));
typedef float   floatx16 __attribute__((ext_vector_type(16)));
typedef float   float4v  __attribute__((ext_vector_type(4)));
typedef uint    uint4v   __attribute__((ext_vector_type(4)));
typedef ushort  ushort4v __attribute__((ext_vector_type(4)));

#define MFMA16(a,b,c) __builtin_amdgcn_mfma_f32_16x16x32_bf16((a),(b),(c),0,0,0)
#define MFMA32(a,b,c) __builtin_amdgcn_mfma_f32_32x32x16_bf16((a),(b),(c),0,0,0)

__device__ __forceinline__ float b2f(ushort u){
  union { uint i; float f; } v; v.i = ((uint)u) << 16; return v.f;
}
__device__ __forceinline__ ushort f2b(float f){   // RNE f32->bf16
  union { float f; uint i; } v; v.f = f;
  uint r = v.i + 0x7FFFu + ((v.i >> 16) & 1u);
  return (ushort)(r >> 16);
}
__device__ __forceinline__ void split2(float f, ushort& h, ushort& l){
  h = f2b(f);
  l = f2b(f - b2f(h));
}
__device__ __forceinline__ void gload16(const ushort* g, ushort* l){
  __builtin_amdgcn_global_load_lds(
      (const __attribute__((address_space(1))) unsigned int*)g,
      (__attribute__((address_space(3))) unsigned int*)l, 16, 0, 0);
}

// ---------------------------------------------------------------------------
// One-time f32 -> (hi,lo) bf16 split converters (memory-bound, vectorized).
// ---------------------------------------------------------------------------
__global__ __launch_bounds__(256) void split_xy(
    const float* __restrict__ x, const float* __restrict__ y,
    ushort* __restrict__ xhi, ushort* __restrict__ xlo,
    ushort* __restrict__ yhi, ushort* __restrict__ ylo)
{
  int idx = blockIdx.x * 256 + threadIdx.x;   // 0 .. 1048575 float4s
  const float* sp; ushort *hp, *lp; int i;
  if (idx < 524288){ sp = x; hp = xhi; lp = xlo; i = idx; }
  else             { sp = y; hp = yhi; lp = ylo; i = idx - 524288; }
  float4v d = ((const float4v*)sp)[i];
  ushort4v h, l;
  #pragma unroll
  for (int j=0;j<4;j++){ ushort hh,ll; split2(d[j],hh,ll); h[j]=hh; l[j]=ll; }
  ((ushort4v*)hp)[i] = h;
  ((ushort4v*)lp)[i] = l;
}

__global__ __launch_bounds__(256) void split_w(
    const float* __restrict__ qw, const float* __restrict__ kw,
    const float* __restrict__ vw, const float* __restrict__ ow,
    ushort* __restrict__ qwh, ushort* __restrict__ qwl,
    ushort* __restrict__ kwh, ushort* __restrict__ kwl,
    ushort* __restrict__ vwh, ushort* __restrict__ vwl,
    ushort* __restrict__ owh, ushort* __restrict__ owl)
{
  int idx = blockIdx.x * 256 + threadIdx.x;   // 0 .. 262143 float4s (4 x 64K)
  int a = idx >> 16, i = idx & 65535;
  const float* sp; ushort *hp, *lp;
  if (a == 0){ sp=qw; hp=qwh; lp=qwl; }
  else if (a == 1){ sp=kw; hp=kwh; lp=kwl; }
  else if (a == 2){ sp=vw; hp=vwh; lp=vwl; }
  else { sp=ow; hp=owh; lp=owl; }
  float4v d = ((const float4v*)sp)[i];
  ushort4v h, l;
  #pragma unroll
  for (int j=0;j<4;j++){ ushort hh,ll; split2(d[j],hh,ll); h[j]=hh; l[j]=ll; }
  ((ushort4v*)hp)[i] = h;
  ((ushort4v*)lp)[i] = l;
}

// ---------------------------------------------------------------------------
// C[M,512] = A[M,512] @ B[512,512]^T + bias.  A,B pre-split bf16 (hi/lo).
// SPLIT_A: 3-MFMA split product (Q/K/V projections). !SPLIT_A: A plain bf16,
// 2 MFMAs (final output proj). Tile BM=128 BN=64 BK=64, dbuf, gload_lds(16),
// row&7 XOR swizzle on 16B blocks (conflict-free octets).
// OUT_MODE 0: f32. 1: hi/lo bf16. 2: plain bf16. KSUM: fused column sums.
// ---------------------------------------------------------------------------
template<int OUT_MODE, bool KSUM, bool SPLIT_A>
__global__ __launch_bounds__(256) void proj2(
    const ushort* __restrict__ Ahi, const ushort* __restrict__ Alo,
    const ushort* __restrict__ Bhi, const ushort* __restrict__ Blo,
    const float* __restrict__ bias,
    float* __restrict__ outf, ushort* __restrict__ outhi, ushort* __restrict__ outlo,
    float* __restrict__ ksum_out)
{
  const int m0 = blockIdx.x * 128;
  const int n0 = blockIdx.y * 64;

  __shared__ __align__(16) ushort AH[2][8192];                 // [128][64]
  __shared__ __align__(16) ushort AL[SPLIT_A?2:1][8192];
  __shared__ __align__(16) ushort BH[2][4096];                 // [64][64]
  __shared__ __align__(16) ushort BL[2][4096];
  __shared__ float cs[64];

  const int t    = threadIdx.x;
  const int lane = t & 63;
  const int w    = t >> 6;
  const int wm   = w >> 1, wn = w & 1;
  const int lr   = lane & 15, lg = lane >> 4;

  // staging geometry: chunk = 1KB = 8 rows of 64 cols; lane l -> row +=(l>>3),
  // 16B block (l&7); global source block pre-swizzled: (l&7) ^ (row&7)=(l>>3).
  const int rl  = lane >> 3;
  const int c8s = (lane & 7) ^ rl;
  constexpr int NCH = SPLIT_A ? 12 : 8;

  auto stage = [&](int buf, int k0){
    #pragma unroll
    for (int j = 0; j < NCH; j++){
      const int c = w * NCH + j;
      if (SPLIT_A){
        if (c < 16){
          int row = c*8 + rl;
          gload16(Ahi + (size_t)(m0+row)*512 + k0 + c8s*8, &AH[buf][c*512]);
        } else if (c < 32){
          int cc = c-16, row = cc*8 + rl;
          gload16(Alo + (size_t)(m0+row)*512 + k0 + c8s*8, &AL[buf][cc*512]);
        } else if (c < 40){
          int cc = c-32, row = cc*8 + rl;
          gload16(Bhi + (size_t)(n0+row)*512 + k0 + c8s*8, &BH[buf][cc*512]);
        } else {
          int cc = c-40, row = cc*8 + rl;
          gload16(Blo + (size_t)(n0+row)*512 + k0 + c8s*8, &BL[buf][cc*512]);
        }
      } else {
        if (c < 16){
          int row = c*8 + rl;
          gload16(Ahi + (size_t)(m0+row)*512 + k0 + c8s*8, &AH[buf][c*512]);
        } else if (c < 24){
          int cc = c-16, row = cc*8 + rl;
          gload16(Bhi + (size_t)(n0+row)*512 + k0 + c8s*8, &BH[buf][cc*512]);
        } else {
          int cc = c-24, row = cc*8 + rl;
          gload16(Blo + (size_t)(n0+row)*512 + k0 + c8s*8, &BL[buf][cc*512]);
        }
      }
    }
  };

  floatx4 zf; zf[0]=0.f; zf[1]=0.f; zf[2]=0.f; zf[3]=0.f;
  floatx4 acc[4][2];
  #pragma unroll
  for (int i=0;i<4;i++)
    #pragma unroll
    for (int j=0;j<2;j++) acc[i][j] = zf;

  stage(0, 0);
  __syncthreads();

  int cur = 0;
  for (int it = 0; it < 8; ++it){
    if (it < 7) stage(cur^1, (it+1)*64);

    const ushort* AHc = AH[cur];
    const ushort* ALc = SPLIT_A ? AL[cur] : nullptr;
    const ushort* BHc = BH[cur];
    const ushort* BLc = BL[cur];

    #pragma unroll
    for (int ks=0; ks<2; ks++){
      const int xo = ((ks*4 + lg) ^ (lr & 7)) << 3;
      bf16x8 ah[4], al[4], bh[2], bl[2];
      #pragma unroll
      for (int mi=0;mi<4;mi++){
        const int off = (wm*64 + mi*16 + lr)*64 + xo;
        ah[mi] = *(const bf16x8*)&AHc[off];
        if (SPLIT_A) al[mi] = *(const bf16x8*)&ALc[off];
      }
      #pragma unroll
      for (int ni=0;ni<2;ni++){
        const int off = (wn*32 + ni*16 + lr)*64 + xo;
        bh[ni] = *(const bf16x8*)&BHc[off];
        bl[ni] = *(const bf16x8*)&BLc[off];
      }
      #pragma unroll
      for (int mi=0;mi<4;mi++)
        #pragma unroll
        for (int ni=0;ni<2;ni++){
          acc[mi][ni] = MFMA16(ah[mi], bh[ni], acc[mi][ni]);
          acc[mi][ni] = MFMA16(ah[mi], bl[ni], acc[mi][ni]);
          if (SPLIT_A) acc[mi][ni] = MFMA16(al[mi], bh[ni], acc[mi][ni]);
        }
    }
    __syncthreads();
    cur ^= 1;
  }

  // epilogue: D frag -> m = lg*4+r, n = lr
  #pragma unroll
  for (int ni=0;ni<2;ni++){
    const int n = n0 + wn*32 + ni*16 + lr;
    const float bn = bias[n];
    #pragma unroll
    for (int mi=0;mi<4;mi++){
      #pragma unroll
      for (int r=0;r<4;r++){
        const int m = m0 + wm*64 + mi*16 + lg*4 + r;
        const float c = acc[mi][ni][r] + bn;
        const size_t off = (size_t)m*512 + n;
        if (OUT_MODE == 0)      { outf[off] = c; }
        else if (OUT_MODE == 1) { ushort h,l; split2(c,h,l); outhi[off]=h; outlo[off]=l; }
        else                    { outhi[off] = f2b(c); }
      }
    }
  }

  if (KSUM) {
    if (t < 64) cs[t] = 0.f;
    __syncthreads();
    #pragma unroll
    for (int ni=0;ni<2;ni++){
      float s = 0.f;
      #pragma unroll
      for (int mi=0;mi<4;mi++)
        #pragma unroll
        for (int r=0;r<4;r++) s += acc[mi][ni][r];
      atomicAdd(&cs[wn*32 + ni*16 + lr], s);
    }
    __syncthreads();
    if (t < 64){
      const int hb = m0 >> 8;
      atomicAdd(&ksum_out[hb*64 + t], cs[t] + 128.f * bias[n0 + t]);
    }
  }
}

// ---------------------------------------------------------------------------
// vt[hb][d][s] = pv[hb][s][d]  (64x64 LDS-tiled transpose)
// ---------------------------------------------------------------------------
__global__ __launch_bounds__(256) void vtrans(
    const ushort* __restrict__ pv, ushort* __restrict__ vt)
{
  const int hb = blockIdx.y;
  const int s0 = blockIdx.x * 64;
  const size_t cb = (size_t)hb * 131072;
  __shared__ __align__(16) ushort T[64][68];
  const int t = threadIdx.x;
  {
    int s = t >> 2, c = (t & 3) * 16;
    *(uint4v*)&T[s][c]     = *(const uint4v*)&pv[cb + (size_t)(s0+s)*64 + c];
    *(uint4v*)&T[s][c + 8] = *(const uint4v*)&pv[cb + (size_t)(s0+s)*64 + c + 8];
  }
  __syncthreads();
  const int d = t >> 2, sc = (t & 3) * 16;
  ushort buf[16];
  #pragma unroll
  for (int i=0;i<16;i++) buf[i] = T[sc + i][d];
  *(uint4v*)&vt[cb + (size_t)d*2048 + s0 + sc]     = *(const uint4v*)&buf[0];
  *(uint4v*)&vt[cb + (size_t)d*2048 + s0 + sc + 8] = *(const uint4v*)&buf[8];
}

// ---------------------------------------------------------------------------
// Fused attention: 128 q-rows/block, 4 waves x 32 q-rows, 32x32x16 MFMA.
// Swapped QK^T: C[key][q] with q = lane&31 -> rm and z are lane-local.
// P built in-register: v_cvt_pk_bf16_f32 + v_permlane32_swap_b32 (T12).
// K/V tiles dbuf'd in LDS (16B-block XOR swizzle, staged via gload_lds).
// ---------------------------------------------------------------------------
__device__ __forceinline__ void stage_tile(
    ushort* khb, ushort* klb, ushort* vtb,
    const ushort* gkhi, const ushort* gklo, const ushort* gvt,
    size_t cb, int kvb, int w, int l)
{
  const int rsub = l >> 3;
  const int c8   = (l & 7) ^ rsub;
  #pragma unroll
  for (int j = 0; j < 6; j++){
    const int chunk = w*6 + j;        // 24 x 1KB: 8 KH, 8 KL, 8 VT
    const int a   = chunk >> 3;
    const int sub = chunk & 7;
    const int row = sub*8 + rsub;
    if (a == 0)
      gload16(gkhi + cb + (size_t)(kvb + row)*64 + c8*8, khb + sub*512);
    else if (a == 1)
      gload16(gklo + cb + (size_t)(kvb + row)*64 + c8*8, klb + sub*512);
    else
      gload16(gvt  + cb + (size_t)row*2048 + kvb + c8*8, vtb + sub*512);
  }
}

__global__ __launch_bounds__(256) void attn_kernel(
    const ushort* __restrict__ qhi, const ushort* __restrict__ qlo,
    const ushort* __restrict__ khi, const ushort* __restrict__ klo,
    const ushort* __restrict__ vt,  const float* __restrict__ ksum,
    ushort* __restrict__ attno)
{
  const int hb = blockIdx.y;
  const int q0 = blockIdx.x * 128;
  const size_t cb = (size_t)hb * 131072;
  const float NF = 0.04419417382415922f;   // 1/sqrt(512)

  __shared__ __align__(16) ushort KH [2][4096];
  __shared__ __align__(16) ushort KL [2][4096];
  __shared__ __align__(16) ushort VTs[2][4096];

  const int t = threadIdx.x, l = t & 63, w = t >> 6;
  const int lq = l & 31, h = l >> 5;

  stage_tile(KH[0], KL[0], VTs[0], khi, klo, vt, cb, 0, w, l);

  // Q frags (swapped-B operand): lane holds Q[q = lq][d = st*16 + h*8 + 0..7]
  union U8 { bf16x8 v; ushort u[8]; };
  U8 qfh[4], qfl[4];
  float part = 0.f;
  #pragma unroll
  for (int st=0; st<4; st++){
    size_t g = cb + (size_t)(q0 + w*32 + lq)*64 + st*16 + h*8;
    qfh[st].v = *(const bf16x8*)&qhi[g];
    qfl[st].v = *(const bf16x8*)&qlo[g];
    float4v k0 = *(const float4v*)&ksum[hb*64 + st*16 + h*8];
    float4v k1 = *(const float4v*)&ksum[hb*64 + st*16 + h*8 + 4];
    #pragma unroll
    for (int j=0;j<4;j++) part += (b2f(qfh[st].u[j])   + b2f(qfl[st].u[j]))   * k0[j];
    #pragma unroll
    for (int j=0;j<4;j++) part += (b2f(qfh[st].u[4+j]) + b2f(qfl[st].u[4+j])) * k1[j];
  }
  part += __shfl_xor(part, 32);            // both d-halves
  const float rm = part * (1.f/2048.f);    // raw row mean for q = lq

  floatx16 O0 = {0,0,0,0,0,0,0,0,0,0,0,0,0,0,0,0};
  floatx16 O1 = O0;
  float zacc = 0.f;

  __syncthreads();                          // tile 0 staged

  int cur = 0;
  for (int kt = 0; kt < 32; kt++){
    if (kt + 1 < 32)
      stage_tile(KH[cur^1], KL[cur^1], VTs[cur^1], khi, klo, vt, cb, (kt+1)*64, w, l);

    const ushort* KHc = KH[cur];
    const ushort* KLc = KL[cur];
    const ushort* VTc = VTs[cur];

    // QK^T swapped: s_g[key][q], key groups g=0,1 (two independent acc chains)
    floatx16 s0 = {0,0,0,0,0,0,0,0,0,0,0,0,0,0,0,0};
    floatx16 s1 = s0;
    #pragma unroll
    for (int st=0; st<4; st++){
      const int xo = (((st*2 + h) ^ (lq & 7)) << 3);
      bf16x8 kh0 = *(const bf16x8*)&KHc[(lq     )*64 + xo];
      bf16x8 kl0 = *(const bf16x8*)&KLc[(lq     )*64 + xo];
      bf16x8 kh1 = *(const bf16x8*)&KHc[(32 + lq)*64 + xo];
      bf16x8 kl1 = *(const bf16x8*)&KLc[(32 + lq)*64 + xo];
      s0 = MFMA32(kh0, qfh[st].v, s0);
      s1 = MFMA32(kh1, qfh[st].v, s1);
      s0 = MFMA32(kh0, qfl[st].v, s0);
      s1 = MFMA32(kh1, qfl[st].v, s1);
      s0 = MFMA32(kl0, qfh[st].v, s0);
      s1 = MFMA32(kl1, qfh[st].v, s1);
    }

    // mask + exp + round-to-bf16 (z uses the SAME rounded p as PV)
    float p0[16], p1[16];
    #pragma unroll
    for (int r=0;r<16;r++){
      float a = s0[r];
      float b = s1[r];
      float pa_ = (a > rm) ? __expf((a - rm) * NF) : 0.f;
      float pb_ = (b > rm) ? __expf((b - rm) * NF) : 0.f;
      pa_ = b2f(f2b(pa_));
      pb_ = b2f(f2b(pb_));
      zacc += pa_ + pb_;
      p0[r] = pa_; p1[r] = pb_;
    }

    // pack P into PV A-frags: keys crow(r,h)=(r&3)+8*(r>>2)+4h -> after one
    // permlane32_swap pair per 8 regs, frag = keys h*8..h*8+7 of 16-key step.
    bf16x8 pa[4];
    #pragma unroll
    for (int g=0; g<2; g++){
      const float* pp = g ? p1 : p0;
      #pragma unroll
      for (int sg=0; sg<2; sg++){
        uint X0,X1,X2,X3;
        asm("v_cvt_pk_bf16_f32 %0, %1, %2" : "=v"(X0) : "v"(pp[sg*8+0]), "v"(pp[sg*8+1]));
        asm("v_cvt_pk_bf16_f32 %0, %1, %2" : "=v"(X1) : "v"(pp[sg*8+2]), "v"(pp[sg*8+3]));
        asm("v_cvt_pk_bf16_f32 %0, %1, %2" : "=v"(X2) : "v"(pp[sg*8+4]), "v"(pp[sg*8+5]));
        asm("v_cvt_pk_bf16_f32 %0, %1, %2" : "=v"(X3) : "v"(pp[sg*8+6]), "v"(pp[sg*8+7]));
        asm("v_permlane32_swap_b32 %0, %1" : "+v"(X0), "+v"(X2));
        asm("v_permlane32_swap_b32 %0, %1" : "+v"(X1), "+v"(X3));
        union { uint u[4]; bf16x8 v; } pu;
        pu.u[0]=X0; pu.u[1]=X1; pu.u[2]=X2; pu.u[3]=X3;
        pa[g*2+sg] = pu.v;
      }
    }

    // PV: O[q][d] += P[q][k] V[k][d]
    #pragma unroll
    for (int s4=0; s4<4; s4++){
      const int xo = (((s4*2 + h) ^ (lq & 7)) << 3);
      bf16x8 vf0 = *(const bf16x8*)&VTc[(lq     )*64 + xo];
      bf16x8 vf1 = *(const bf16x8*)&VTc[(32 + lq)*64 + xo];
      O0 = MFMA32(pa[s4], vf0, O0);
      O1 = MFMA32(pa[s4], vf1, O1);
    }

    __syncthreads();
    cur ^= 1;
  }

  // epilogue: z[q=lq] = zacc + partner-half; normalize + write bf16
  zacc += __shfl_xor(zacc, 32);
  const float zinv = 1.f / zacc;
  #pragma unroll
  for (int r=0;r<16;r++){
    const int crow = (r&3) + ((r>>2)<<3) + (h<<2);
    const float zi = __shfl(zinv, crow);
    const int q = q0 + w*32 + crow;
    const size_t base = cb + (size_t)q*64 + lq;
    attno[base]      = f2b(O0[r] * zi);
    attno[base + 32] = f2b(O1[r] * zi);
  }
}

// ---------------------------------------------------------------------------
extern "C" void kernel_launch(void* const* d_in, const int* in_sizes, int n_in,
                              void* d_out, int out_size, void* d_ws, size_t ws_size,
                              hipStream_t stream)
{
  const float* x   = (const float*)d_in[0];
  const float* y   = (const float*)d_in[1];
  const float* q_w = (const float*)d_in[2];
  const float* q_b = (const float*)d_in[3];
  const float* k_w = (const float*)d_in[4];
  const float* k_b = (const float*)d_in[5];
  const float* v_w = (const float*)d_in[6];
  const float* v_b = (const float*)d_in[7];
  const float* o_w = (const float*)d_in[8];
  const float* o_b = (const float*)d_in[9];

  const size_t NE = 4096ull * 512;     // 2,097,152
  const size_t WN = 512ull * 512;      // 262,144
  ushort* p = (ushort*)d_ws;
  ushort* pq_hi = p;                   // 5 x NE: projections
  ushort* pq_lo = pq_hi + NE;
  ushort* pk_hi = pq_lo + NE;
  ushort* pk_lo = pk_hi + NE;
  ushort* pv    = pk_lo + NE;
  ushort* xhi   = pv + NE;             // 4 x NE: split inputs
  ushort* xlo   = xhi + NE;
  ushort* yhi   = xlo + NE;
  ushort* ylo   = yhi + NE;
  ushort* vtg   = xhi;                 // alias: xhi dead after Q-proj
  ushort* attno = xlo;                 // alias: xlo dead after Q-proj
  ushort* qwh = ylo + NE;              // 8 x WN: split weights
  ushort* qwl = qwh + WN;
  ushort* kwh = qwl + WN;
  ushort* kwl = kwh + WN;
  ushort* vwh = kwl + WN;
  ushort* vwl = vwh + WN;
  ushort* owh = vwl + WN;
  ushort* owl = owh + WN;
  float*  ksumb = (float*)(owl + WN);

  hipMemsetAsync(ksumb, 0, 16 * 64 * sizeof(float), stream);

  split_xy<<<4096, 256, 0, stream>>>(x, y, xhi, xlo, yhi, ylo);
  split_w <<<1024, 256, 0, stream>>>(q_w, k_w, v_w, o_w,
                                     qwh, qwl, kwh, kwl, vwh, vwl, owh, owl);

  dim3 gg(32, 8), bb(256);
  proj2<1,false,true ><<<gg, bb, 0, stream>>>(xhi, xlo, qwh, qwl, q_b, nullptr, pq_hi, pq_lo, nullptr);
  proj2<1,true ,true ><<<gg, bb, 0, stream>>>(yhi, ylo, kwh, kwl, k_b, nullptr, pk_hi, pk_lo, ksumb);
  proj2<2,false,true ><<<gg, bb, 0, stream>>>(yhi, ylo, vwh, vwl, v_b, nullptr, pv, nullptr, nullptr);
  vtrans<<<dim3(32,16), 256, 0, stream>>>(pv, vtg);
  attn_kernel<<<dim3(16,16), 256, 0, stream>>>(pq_hi, pq_lo, pk_hi, pk_lo, vtg, ksumb, attno);
  proj2<0,false,false><<<gg, bb, 0, stream>>>(attno, nullptr, owh, owl, o_b, (float*)d_out, nullptr, nullptr, nullptr);
}

// Round 5
// 115.225 us; speedup vs baseline: 2.6670x; 1.1649x over previous
//
#include <hip/hip_runtime.h>

// Mutihead_Attention: x,y [2,2048,512] f32. Flat-reshape => head-batch hb owns
// contiguous [2048,64] chunk at hb*131072 of each [4096,512] projection.
// scores=QK^T/sqrt(512); mask score<=rowmean; softmax; PV; @o_w^T+o_b.
// rowmean_i = q_i.ksum/2048 (ksum fused in K-proj epilogue).
// R5: occupancy was the binding constraint (grid 256 = 1 block/CU, 1 wave/SIMD).
// attn: 512-thread blocks, 8 waves = 4 q-groups x 2 kv-halves; partial (O,z)
// combine by plain addition in LDS (no running max -> no rescale). 96KB LDS.
// proj GEMMs: BM=64, grid (64,8)=512 blocks -> 2 blocks/CU.

typedef unsigned short ushort;
typedef unsigned int uint;

typedef __bf16  bf16x8   __attribute__((ext_vector_type(8)));
typedef float   floatx4  __attribute__((ext_vector_type(4)));
typedef float   floatx16 __attribute__((ext_vector_type(16)));
typedef float   float4v  __attribute__((ext_vector_type(4)));
typedef uint    uint4v   __attribute__((ext_vector_type(4)));
typedef ushort  ushort4v __attribute__((ext_vector_type(4)));

#define MFMA16(a,b,c) __builtin_amdgcn_mfma_f32_16x16x32_bf16((a),(b),(c),0,0,0)
#define MFMA32(a,b,c) __builtin_amdgcn_mfma_f32_32x32x16_bf16((a),(b),(c),0,0,0)

__device__ __forceinline__ float b2f(ushort u){
  union { uint i; float f; } v; v.i = ((uint)u) << 16; return v.f;
}
__device__ __forceinline__ ushort f2b(float f){   // RNE f32->bf16
  union { float f; uint i; } v; v.f = f;
  uint r = v.i + 0x7FFFu + ((v.i >> 16) & 1u);
  return (ushort)(r >> 16);
}
__device__ __forceinline__ void split2(float f, ushort& h, ushort& l){
  h = f2b(f);
  l = f2b(f - b2f(h));
}
__device__ __forceinline__ void gload16(const ushort* g, ushort* l){
  __builtin_amdgcn_global_load_lds(
      (const __attribute__((address_space(1))) unsigned int*)g,
      (__attribute__((address_space(3))) unsigned int*)l, 16, 0, 0);
}

// ---------------------------------------------------------------------------
// One-time f32 -> (hi,lo) bf16 split converters.
// ---------------------------------------------------------------------------
__global__ __launch_bounds__(256) void split_xy(
    const float* __restrict__ x, const float* __restrict__ y,
    ushort* __restrict__ xhi, ushort* __restrict__ xlo,
    ushort* __restrict__ yhi, ushort* __restrict__ ylo)
{
  int idx = blockIdx.x * 256 + threadIdx.x;   // 0 .. 1048575 float4s
  const float* sp; ushort *hp, *lp; int i;
  if (idx < 524288){ sp = x; hp = xhi; lp = xlo; i = idx; }
  else             { sp = y; hp = yhi; lp = ylo; i = idx - 524288; }
  float4v d = ((const float4v*)sp)[i];
  ushort4v h, l;
  #pragma unroll
  for (int j=0;j<4;j++){ ushort hh,ll; split2(d[j],hh,ll); h[j]=hh; l[j]=ll; }
  ((ushort4v*)hp)[i] = h;
  ((ushort4v*)lp)[i] = l;
}

__global__ __launch_bounds__(256) void split_w(
    const float* __restrict__ qw, const float* __restrict__ kw,
    const float* __restrict__ vw, const float* __restrict__ ow,
    ushort* __restrict__ qwh, ushort* __restrict__ qwl,
    ushort* __restrict__ kwh, ushort* __restrict__ kwl,
    ushort* __restrict__ vwh, ushort* __restrict__ vwl,
    ushort* __restrict__ owh, ushort* __restrict__ owl)
{
  int idx = blockIdx.x * 256 + threadIdx.x;   // 0 .. 262143 float4s
  int a = idx >> 16, i = idx & 65535;
  const float* sp; ushort *hp, *lp;
  if (a == 0){ sp=qw; hp=qwh; lp=qwl; }
  else if (a == 1){ sp=kw; hp=kwh; lp=kwl; }
  else if (a == 2){ sp=vw; hp=vwh; lp=vwl; }
  else { sp=ow; hp=owh; lp=owl; }
  float4v d = ((const float4v*)sp)[i];
  ushort4v h, l;
  #pragma unroll
  for (int j=0;j<4;j++){ ushort hh,ll; split2(d[j],hh,ll); h[j]=hh; l[j]=ll; }
  ((ushort4v*)hp)[i] = h;
  ((ushort4v*)lp)[i] = l;
}

// ---------------------------------------------------------------------------
// C[M,512] = A[M,512] @ B[512,512]^T + bias.  A,B pre-split bf16 (hi/lo).
// BM=64 BN=64 BK=64, grid (64,8)=512 blocks (2 blocks/CU), dbuf, gload_lds(16),
// row&7 XOR swizzle on 16B blocks. SPLIT_A: 3-MFMA split product; else 2.
// OUT_MODE 0: f32. 1: hi/lo bf16. 2: plain bf16. KSUM: fused column sums.
// ---------------------------------------------------------------------------
template<int OUT_MODE, bool KSUM, bool SPLIT_A>
__global__ __launch_bounds__(256) void proj2(
    const ushort* __restrict__ Ahi, const ushort* __restrict__ Alo,
    const ushort* __restrict__ Bhi, const ushort* __restrict__ Blo,
    const float* __restrict__ bias,
    float* __restrict__ outf, ushort* __restrict__ outhi, ushort* __restrict__ outlo,
    float* __restrict__ ksum_out)
{
  const int m0 = blockIdx.x * 64;
  const int n0 = blockIdx.y * 64;

  __shared__ __align__(16) ushort AH[2][4096];                 // [64][64]
  __shared__ __align__(16) ushort AL[SPLIT_A?2:1][4096];
  __shared__ __align__(16) ushort BH[2][4096];
  __shared__ __align__(16) ushort BL[2][4096];
  __shared__ float cs[64];

  const int t    = threadIdx.x;
  const int lane = t & 63;
  const int w    = t >> 6;
  const int wm   = w >> 1, wn = w & 1;
  const int lr   = lane & 15, lg = lane >> 4;

  const int rl  = lane >> 3;
  const int c8s = (lane & 7) ^ rl;       // pre-swizzled source 16B block
  constexpr int NCH = SPLIT_A ? 8 : 6;

  auto stage = [&](int buf, int k0){
    #pragma unroll
    for (int j = 0; j < NCH; j++){
      const int c = w * NCH + j;
      if (SPLIT_A){
        if (c < 8)
          gload16(Ahi + (size_t)(m0 + c*8 + rl)*512 + k0 + c8s*8, &AH[buf][c*512]);
        else if (c < 16)
          gload16(Alo + (size_t)(m0 + (c-8)*8 + rl)*512 + k0 + c8s*8, &AL[buf][(c-8)*512]);
        else if (c < 24)
          gload16(Bhi + (size_t)(n0 + (c-16)*8 + rl)*512 + k0 + c8s*8, &BH[buf][(c-16)*512]);
        else
          gload16(Blo + (size_t)(n0 + (c-24)*8 + rl)*512 + k0 + c8s*8, &BL[buf][(c-24)*512]);
      } else {
        if (c < 8)
          gload16(Ahi + (size_t)(m0 + c*8 + rl)*512 + k0 + c8s*8, &AH[buf][c*512]);
        else if (c < 16)
          gload16(Bhi + (size_t)(n0 + (c-8)*8 + rl)*512 + k0 + c8s*8, &BH[buf][(c-8)*512]);
        else
          gload16(Blo + (size_t)(n0 + (c-16)*8 + rl)*512 + k0 + c8s*8, &BL[buf][(c-16)*512]);
      }
    }
  };

  floatx4 zf; zf[0]=0.f; zf[1]=0.f; zf[2]=0.f; zf[3]=0.f;
  floatx4 acc[2][2];
  #pragma unroll
  for (int i=0;i<2;i++)
    #pragma unroll
    for (int j=0;j<2;j++) acc[i][j] = zf;

  stage(0, 0);
  __syncthreads();

  int cur = 0;
  for (int it = 0; it < 8; ++it){
    if (it < 7) stage(cur^1, (it+1)*64);

    const ushort* AHc = AH[cur];
    const ushort* ALc = SPLIT_A ? AL[cur] : nullptr;
    const ushort* BHc = BH[cur];
    const ushort* BLc = BL[cur];

    #pragma unroll
    for (int ks=0; ks<2; ks++){
      const int xo = ((ks*4 + lg) ^ (lr & 7)) << 3;
      bf16x8 ah[2], al[2], bh[2], bl[2];
      #pragma unroll
      for (int mi=0;mi<2;mi++){
        const int off = (wm*32 + mi*16 + lr)*64 + xo;
        ah[mi] = *(const bf16x8*)&AHc[off];
        if (SPLIT_A) al[mi] = *(const bf16x8*)&ALc[off];
      }
      #pragma unroll
      for (int ni=0;ni<2;ni++){
        const int off = (wn*32 + ni*16 + lr)*64 + xo;
        bh[ni] = *(const bf16x8*)&BHc[off];
        bl[ni] = *(const bf16x8*)&BLc[off];
      }
      #pragma unroll
      for (int mi=0;mi<2;mi++)
        #pragma unroll
        for (int ni=0;ni<2;ni++){
          acc[mi][ni] = MFMA16(ah[mi], bh[ni], acc[mi][ni]);
          acc[mi][ni] = MFMA16(ah[mi], bl[ni], acc[mi][ni]);
          if (SPLIT_A) acc[mi][ni] = MFMA16(al[mi], bh[ni], acc[mi][ni]);
        }
    }
    __syncthreads();
    cur ^= 1;
  }

  // epilogue: D frag -> m = lg*4+r, n = lr
  #pragma unroll
  for (int ni=0;ni<2;ni++){
    const int n = n0 + wn*32 + ni*16 + lr;
    const float bn = bias[n];
    #pragma unroll
    for (int mi=0;mi<2;mi++){
      #pragma unroll
      for (int r=0;r<4;r++){
        const int m = m0 + wm*32 + mi*16 + lg*4 + r;
        const float c = acc[mi][ni][r] + bn;
        const size_t off = (size_t)m*512 + n;
        if (OUT_MODE == 0)      { outf[off] = c; }
        else if (OUT_MODE == 1) { ushort h,l; split2(c,h,l); outhi[off]=h; outlo[off]=l; }
        else                    { outhi[off] = f2b(c); }
      }
    }
  }

  if (KSUM) {
    if (t < 64) cs[t] = 0.f;
    __syncthreads();
    #pragma unroll
    for (int ni=0;ni<2;ni++){
      float s = 0.f;
      #pragma unroll
      for (int mi=0;mi<2;mi++)
        #pragma unroll
        for (int r=0;r<4;r++) s += acc[mi][ni][r];
      atomicAdd(&cs[wn*32 + ni*16 + lr], s);
    }
    __syncthreads();
    if (t < 64){
      const int hb = m0 >> 8;
      atomicAdd(&ksum_out[hb*64 + t], cs[t] + 64.f * bias[n0 + t]);
    }
  }
}

// ---------------------------------------------------------------------------
// vt[hb][d][s] = pv[hb][s][d]  (64x64 LDS-tiled transpose)
// ---------------------------------------------------------------------------
__global__ __launch_bounds__(256) void vtrans(
    const ushort* __restrict__ pv, ushort* __restrict__ vt)
{
  const int hb = blockIdx.y;
  const int s0 = blockIdx.x * 64;
  const size_t cb = (size_t)hb * 131072;
  __shared__ __align__(16) ushort T[64][68];
  const int t = threadIdx.x;
  {
    int s = t >> 2, c = (t & 3) * 16;
    *(uint4v*)&T[s][c]     = *(const uint4v*)&pv[cb + (size_t)(s0+s)*64 + c];
    *(uint4v*)&T[s][c + 8] = *(const uint4v*)&pv[cb + (size_t)(s0+s)*64 + c + 8];
  }
  __syncthreads();
  const int d = t >> 2, sc = (t & 3) * 16;
  ushort buf[16];
  #pragma unroll
  for (int i=0;i<16;i++) buf[i] = T[sc + i][d];
  *(uint4v*)&vt[cb + (size_t)d*2048 + s0 + sc]     = *(const uint4v*)&buf[0];
  *(uint4v*)&vt[cb + (size_t)d*2048 + s0 + sc + 8] = *(const uint4v*)&buf[8];
}

// ---------------------------------------------------------------------------
// Fused attention: 128 q-rows/block, 8 waves = 4 q-groups (32 q each, 32x32x16
// MFMA, swapped QK^T) x 2 kv-halves. Partial (O,z) summed in LDS at the end
// (no running max -> plain addition). In-register P via cvt_pk + permlane32.
// ---------------------------------------------------------------------------
__device__ __forceinline__ void stage_tile(
    ushort* khb, ushort* klb, ushort* vtb,
    const ushort* gkhi, const ushort* gklo, const ushort* gvt,
    size_t cb, int kvb, int ws, int l)
{
  const int rsub = l >> 3;
  const int c8   = (l & 7) ^ rsub;
  #pragma unroll
  for (int j = 0; j < 6; j++){
    const int chunk = ws*6 + j;       // 24 x 1KB: 8 KH, 8 KL, 8 VT
    const int a   = chunk >> 3;
    const int sub = chunk & 7;
    const int row = sub*8 + rsub;
    if (a == 0)
      gload16(gkhi + cb + (size_t)(kvb + row)*64 + c8*8, khb + sub*512);
    else if (a == 1)
      gload16(gklo + cb + (size_t)(kvb + row)*64 + c8*8, klb + sub*512);
    else
      gload16(gvt  + cb + (size_t)row*2048 + kvb + c8*8, vtb + sub*512);
  }
}

__global__ __launch_bounds__(512) void attn_kernel(
    const ushort* __restrict__ qhi, const ushort* __restrict__ qlo,
    const ushort* __restrict__ khi, const ushort* __restrict__ klo,
    const ushort* __restrict__ vt,  const float* __restrict__ ksum,
    ushort* __restrict__ attno)
{
  const int hb = blockIdx.y;
  const int q0 = blockIdx.x * 128;
  const size_t cb = (size_t)hb * 131072;
  const float NF = 0.04419417382415922f;   // 1/sqrt(512)

  __shared__ __align__(16) ushort TILES[2][2][3][4096];  // [half][buf][KH,KL,VT]

  const int t = threadIdx.x, l = t & 63, w = t >> 6;
  const int half = w >> 2, ws = w & 3;
  const int lq = l & 31, h = l >> 5;
  const int kbase = half * 1024;

  stage_tile(TILES[half][0][0], TILES[half][0][1], TILES[half][0][2],
             khi, klo, vt, cb, kbase, ws, l);

  // Q frags (swapped-B operand): lane holds Q[q = lq][d = st*16 + h*8 + 0..7]
  union U8 { bf16x8 v; ushort u[8]; };
  U8 qfh[4], qfl[4];
  float part = 0.f;
  #pragma unroll
  for (int st=0; st<4; st++){
    size_t g = cb + (size_t)(q0 + ws*32 + lq)*64 + st*16 + h*8;
    qfh[st].v = *(const bf16x8*)&qhi[g];
    qfl[st].v = *(const bf16x8*)&qlo[g];
    float4v k0 = *(const float4v*)&ksum[hb*64 + st*16 + h*8];
    float4v k1 = *(const float4v*)&ksum[hb*64 + st*16 + h*8 + 4];
    #pragma unroll
    for (int j=0;j<4;j++) part += (b2f(qfh[st].u[j])   + b2f(qfl[st].u[j]))   * k0[j];
    #pragma unroll
    for (int j=0;j<4;j++) part += (b2f(qfh[st].u[4+j]) + b2f(qfl[st].u[4+j])) * k1[j];
  }
  part += __shfl_xor(part, 32);            // both d-halves
  const float rm = part * (1.f/2048.f);    // raw row mean for q = lq

  floatx16 O0 = {0,0,0,0,0,0,0,0,0,0,0,0,0,0,0,0};
  floatx16 O1 = O0;
  float zacc = 0.f;

  __syncthreads();                          // tile 0 staged

  int cur = 0;
  for (int kt = 0; kt < 16; kt++){
    if (kt + 1 < 16)
      stage_tile(TILES[half][cur^1][0], TILES[half][cur^1][1], TILES[half][cur^1][2],
                 khi, klo, vt, cb, kbase + (kt+1)*64, ws, l);

    const ushort* KHc = TILES[half][cur][0];
    const ushort* KLc = TILES[half][cur][1];
    const ushort* VTc = TILES[half][cur][2];

    // QK^T swapped: s_g[key][q], key groups g=0,1
    floatx16 s0 = {0,0,0,0,0,0,0,0,0,0,0,0,0,0,0,0};
    floatx16 s1 = s0;
    #pragma unroll
    for (int st=0; st<4; st++){
      const int xo = (((st*2 + h) ^ (lq & 7)) << 3);
      bf16x8 kh0 = *(const bf16x8*)&KHc[(lq     )*64 + xo];
      bf16x8 kl0 = *(const bf16x8*)&KLc[(lq     )*64 + xo];
      bf16x8 kh1 = *(const bf16x8*)&KHc[(32 + lq)*64 + xo];
      bf16x8 kl1 = *(const bf16x8*)&KLc[(32 + lq)*64 + xo];
      s0 = MFMA32(kh0, qfh[st].v, s0);
      s1 = MFMA32(kh1, qfh[st].v, s1);
      s0 = MFMA32(kh0, qfl[st].v, s0);
      s1 = MFMA32(kh1, qfl[st].v, s1);
      s0 = MFMA32(kl0, qfh[st].v, s0);
      s1 = MFMA32(kl1, qfh[st].v, s1);
    }

    // mask + exp + round-to-bf16 (z uses the SAME rounded p as PV)
    float p0[16], p1[16];
    #pragma unroll
    for (int r=0;r<16;r++){
      float a = s0[r];
      float b = s1[r];
      float pa_ = (a > rm) ? __expf((a - rm) * NF) : 0.f;
      float pb_ = (b > rm) ? __expf((b - rm) * NF) : 0.f;
      pa_ = b2f(f2b(pa_));
      pb_ = b2f(f2b(pb_));
      zacc += pa_ + pb_;
      p0[r] = pa_; p1[r] = pb_;
    }

    // pack P into PV A-frags (cvt_pk + permlane32_swap; verified R4 layout)
    bf16x8 pa[4];
    #pragma unroll
    for (int g=0; g<2; g++){
      const float* pp = g ? p1 : p0;
      #pragma unroll
      for (int sg=0; sg<2; sg++){
        uint X0,X1,X2,X3;
        asm("v_cvt_pk_bf16_f32 %0, %1, %2" : "=v"(X0) : "v"(pp[sg*8+0]), "v"(pp[sg*8+1]));
        asm("v_cvt_pk_bf16_f32 %0, %1, %2" : "=v"(X1) : "v"(pp[sg*8+2]), "v"(pp[sg*8+3]));
        asm("v_cvt_pk_bf16_f32 %0, %1, %2" : "=v"(X2) : "v"(pp[sg*8+4]), "v"(pp[sg*8+5]));
        asm("v_cvt_pk_bf16_f32 %0, %1, %2" : "=v"(X3) : "v"(pp[sg*8+6]), "v"(pp[sg*8+7]));
        asm("v_permlane32_swap_b32 %0, %1" : "+v"(X0), "+v"(X2));
        asm("v_permlane32_swap_b32 %0, %1" : "+v"(X1), "+v"(X3));
        union { uint u[4]; bf16x8 v; } pu;
        pu.u[0]=X0; pu.u[1]=X1; pu.u[2]=X2; pu.u[3]=X3;
        pa[g*2+sg] = pu.v;
      }
    }

    // PV: O[q][d] += P[q][k] V[k][d]
    #pragma unroll
    for (int s4=0; s4<4; s4++){
      const int xo = (((s4*2 + h) ^ (lq & 7)) << 3);
      bf16x8 vf0 = *(const bf16x8*)&VTc[(lq     )*64 + xo];
      bf16x8 vf1 = *(const bf16x8*)&VTc[(32 + lq)*64 + xo];
      O0 = MFMA32(pa[s4], vf0, O0);
      O1 = MFMA32(pa[s4], vf1, O1);
    }

    __syncthreads();
    cur ^= 1;
  }

  // cross-half combine: partial (O,z) add via LDS (reuse tile space)
  zacc += __shfl_xor(zacc, 32);
  float* CB = (float*)&TILES[0][0][0][0];
  const int ci = (ws*64 + l)*34;
  if (half == 1){
    #pragma unroll
    for (int i=0;i<16;i++){ CB[ci+i] = O0[i]; CB[ci+16+i] = O1[i]; }
    CB[ci+32] = zacc;
  }
  __syncthreads();
  if (half == 0){
    const float zinv = 1.f / (zacc + CB[ci+32]);
    #pragma unroll
    for (int r=0;r<16;r++){ O0[r] += CB[ci+r]; O1[r] += CB[ci+16+r]; }
    #pragma unroll
    for (int r=0;r<16;r++){
      const int crow = (r&3) + ((r>>2)<<3) + (h<<2);
      const float zi = __shfl(zinv, crow);
      const int q = q0 + ws*32 + crow;
      const size_t base = cb + (size_t)q*64 + lq;
      attno[base]      = f2b(O0[r] * zi);
      attno[base + 32] = f2b(O1[r] * zi);
    }
  }
}

// ---------------------------------------------------------------------------
extern "C" void kernel_launch(void* const* d_in, const int* in_sizes, int n_in,
                              void* d_out, int out_size, void* d_ws, size_t ws_size,
                              hipStream_t stream)
{
  const float* x   = (const float*)d_in[0];
  const float* y   = (const float*)d_in[1];
  const float* q_w = (const float*)d_in[2];
  const float* q_b = (const float*)d_in[3];
  const float* k_w = (const float*)d_in[4];
  const float* k_b = (const float*)d_in[5];
  const float* v_w = (const float*)d_in[6];
  const float* v_b = (const float*)d_in[7];
  const float* o_w = (const float*)d_in[8];
  const float* o_b = (const float*)d_in[9];

  const size_t NE = 4096ull * 512;     // 2,097,152
  const size_t WN = 512ull * 512;      // 262,144
  ushort* p = (ushort*)d_ws;
  ushort* pq_hi = p;                   // 5 x NE: projections
  ushort* pq_lo = pq_hi + NE;
  ushort* pk_hi = pq_lo + NE;
  ushort* pk_lo = pk_hi + NE;
  ushort* pv    = pk_lo + NE;
  ushort* xhi   = pv + NE;             // 4 x NE: split inputs
  ushort* xlo   = xhi + NE;
  ushort* yhi   = xlo + NE;
  ushort* ylo   = yhi + NE;
  ushort* vtg   = xhi;                 // alias: xhi dead after Q-proj
  ushort* attno = xlo;                 // alias: xlo dead after Q-proj
  ushort* qwh = ylo + NE;              // 8 x WN: split weights
  ushort* qwl = qwh + WN;
  ushort* kwh = qwl + WN;
  ushort* kwl = kwh + WN;
  ushort* vwh = kwl + WN;
  ushort* vwl = vwh + WN;
  ushort* owh = vwl + WN;
  ushort* owl = owh + WN;
  float*  ksumb = (float*)(owl + WN);

  hipMemsetAsync(ksumb, 0, 16 * 64 * sizeof(float), stream);

  split_xy<<<4096, 256, 0, stream>>>(x, y, xhi, xlo, yhi, ylo);
  split_w <<<1024, 256, 0, stream>>>(q_w, k_w, v_w, o_w,
                                     qwh, qwl, kwh, kwl, vwh, vwl, owh, owl);

  dim3 gg(64, 8), bb(256);
  proj2<1,false,true ><<<gg, bb, 0, stream>>>(xhi, xlo, qwh, qwl, q_b, nullptr, pq_hi, pq_lo, nullptr);
  proj2<1,true ,true ><<<gg, bb, 0, stream>>>(yhi, ylo, kwh, kwl, k_b, nullptr, pk_hi, pk_lo, ksumb);
  proj2<2,false,true ><<<gg, bb, 0, stream>>>(yhi, ylo, vwh, vwl, v_b, nullptr, pv, nullptr, nullptr);
  vtrans<<<dim3(32,16), 256, 0, stream>>>(pv, vtg);
  attn_kernel<<<dim3(16,16), 512, 0, stream>>>(pq_hi, pq_lo, pk_hi, pk_lo, vtg, ksumb, attno);
  proj2<0,false,false><<<gg, bb, 0, stream>>>(attno, nullptr, owh, owl, o_b, (float*)d_out, nullptr, nullptr, nullptr);
}